// Round 3
// baseline (1885.203 us; speedup 1.0000x reference)
//
#include <hip/hip_runtime.h>

#define N_NODES 200000
#define N_EDGES 6400000

constexpr int BSHIFT = 9;                      // 512 nodes per bucket
constexpr int NBUCK  = (N_NODES + 511) / 512;  // 391
constexpr int CHUNK  = 16384;
constexpr int NCHUNK = (N_EDGES + CHUNK - 1) / CHUNK;  // 391
constexpr int MAXBUCK = 18432;                 // lambda=16384, +16 sigma

// ---- edge index load helper: handles int32 or int64 storage ----
__device__ __forceinline__ int ld_edge(const void* ei, int is64, int idx) {
    return is64 ? (int)((const long long*)ei)[idx] : ((const int*)ei)[idx];
}

__global__ void k_zero(int* __restrict__ p, int n) {
    int i = blockIdx.x * blockDim.x + threadIdx.x;
    if (i < n) p[i] = 0;
}

// int64 little-endian values < 2^31  =>  every odd u32 slot is 0
__global__ void k_detect(const unsigned int* __restrict__ ei, int* __restrict__ flag) {
    __shared__ int nz;
    if (threadIdx.x == 0) nz = 0;
    __syncthreads();
    if (ei[2 * threadIdx.x + 1] != 0u) atomicOr(&nz, 1);
    __syncthreads();
    if (threadIdx.x == 0) *flag = nz ? 0 : 1;
}

// bucket histogram: LDS-accumulated, one global atomic per bucket per block
__global__ void k_hist(const void* __restrict__ ei, const int* __restrict__ flag,
                       int* __restrict__ bucketCnt) {
    __shared__ int h[NBUCK];
    for (int i = threadIdx.x; i < NBUCK; i += 256) h[i] = 0;
    __syncthreads();
    const int is64 = *flag;
    int stride = gridDim.x * blockDim.x;
    for (int e = blockIdx.x * 256 + threadIdx.x; e < N_EDGES; e += stride) {
        int d = ld_edge(ei, is64, N_EDGES + e);
        atomicAdd(&h[d >> BSHIFT], 1);
    }
    __syncthreads();
    for (int i = threadIdx.x; i < NBUCK; i += 256)
        if (h[i]) atomicAdd(&bucketCnt[i], h[i]);
}

// single-block scan of 391 bucket counts -> exclusive bases + cursors
__global__ void k_scan_buckets(const int* __restrict__ bucketCnt,
                               int* __restrict__ bucketBase,
                               int* __restrict__ bucketCursor) {
    __shared__ int sc[512];
    int t = threadIdx.x;
    sc[t]       = (t < NBUCK)       ? bucketCnt[t]       : 0;
    sc[t + 256] = (t + 256 < NBUCK) ? bucketCnt[t + 256] : 0;
    __syncthreads();
    for (int off = 1; off < 512; off <<= 1) {
        int a0 = (t >= off) ? sc[t - off] : 0;
        int a1 = sc[t + 256 - off];
        __syncthreads();
        sc[t] += a0; sc[t + 256] += a1;
        __syncthreads();
    }
    for (int i = t; i < NBUCK; i += 256) {
        int excl = sc[i] - bucketCnt[i];
        bucketBase[i] = excl;
        bucketCursor[i] = excl;
    }
    if (t == 0) bucketBase[NBUCK] = N_EDGES;
}

// level-1: bin a 16K-edge chunk by bucket in LDS, write contiguous runs
__global__ void __launch_bounds__(256)
k_binscatter(const void* __restrict__ ei, const int* __restrict__ flag,
             int* __restrict__ bucketCursor, unsigned int* __restrict__ bin) {
    __shared__ int hist[NBUCK];
    __shared__ int pref[NBUCK + 1];
    __shared__ int cur[NBUCK];
    __shared__ int gb[NBUCK];
    __shared__ int sc[512];
    __shared__ unsigned int stage[CHUNK];
    const int is64 = *flag;
    int b = blockIdx.x, t = threadIdx.x;
    int e0 = b * CHUNK;
    int n = min(CHUNK, N_EDGES - e0);
    for (int i = t; i < NBUCK; i += 256) hist[i] = 0;
    __syncthreads();
    // pass A: per-chunk bucket histogram
    for (int i = t; i < n; i += 256) {
        int d = ld_edge(ei, is64, N_EDGES + e0 + i);
        atomicAdd(&hist[d >> BSHIFT], 1);
    }
    __syncthreads();
    // scan histogram (512-slot Hillis-Steele)
    sc[t]       = (t < NBUCK)       ? hist[t]       : 0;
    sc[t + 256] = (t + 256 < NBUCK) ? hist[t + 256] : 0;
    __syncthreads();
    for (int off = 1; off < 512; off <<= 1) {
        int a0 = (t >= off) ? sc[t - off] : 0;
        int a1 = sc[t + 256 - off];
        __syncthreads();
        sc[t] += a0; sc[t + 256] += a1;
        __syncthreads();
    }
    for (int i = t; i < NBUCK; i += 256) {
        int excl = sc[i] - hist[i];
        pref[i] = excl;
        cur[i] = excl;
    }
    if (t == 0) pref[NBUCK] = n;
    __syncthreads();
    // pass B: scatter packed (local_d<<18 | src) into LDS stage, bucket-grouped
    for (int i = t; i < n; i += 256) {
        int s = ld_edge(ei, is64, e0 + i);
        int d = ld_edge(ei, is64, N_EDGES + e0 + i);
        int bk = d >> BSHIFT;
        int p = atomicAdd(&cur[bk], 1);
        stage[p] = ((unsigned int)(d & 511) << 18) | (unsigned int)s;
    }
    __syncthreads();
    // reserve global ranges, one atomic per non-empty bucket
    for (int i = t; i < NBUCK; i += 256) {
        int c = hist[i];
        gb[i] = c ? atomicAdd(&bucketCursor[i], c) : 0;
    }
    __syncthreads();
    // write out contiguous runs (binary-search bucket per slot)
    for (int p = t; p < n; p += 256) {
        int lo = 0, hi = NBUCK;
        while (hi - lo > 1) {
            int mid = (lo + hi) >> 1;
            if (pref[mid] <= p) lo = mid; else hi = mid;
        }
        bin[gb[lo] + (p - pref[lo])] = stage[p];
    }
}

// level-2: one block per bucket. Re-sort the bucket's edges by SRC-BIN
// (src>>9) for gather locality in k_agg_lds, and produce dinv from the
// per-node degree counts (rowptr no longer needed).
__global__ void __launch_bounds__(256)
k_bucketsort(const int* __restrict__ bucketBase, unsigned int* __restrict__ bin,
             float* __restrict__ dinv) {
    __shared__ int cntS[512];
    __shared__ int scS[512];
    __shared__ int curS[512];
    __shared__ int cntD[512];
    __shared__ unsigned int payload[MAXBUCK];
    int b = blockIdx.x, t = threadIdx.x;
    int base = bucketBase[b], end = bucketBase[b + 1];
    int n = end - base;
    cntS[t] = 0; cntS[t + 256] = 0;
    cntD[t] = 0; cntD[t + 256] = 0;
    __syncthreads();
    // pass A: src-bin histogram + per-node (dst) degree
    for (int i = t; i < n; i += 256) {
        unsigned int u = bin[base + i];
        atomicAdd(&cntS[(u & 0x3FFFFu) >> BSHIFT], 1);
        atomicAdd(&cntD[u >> 18], 1);
    }
    __syncthreads();
    // scan cntS (512-slot Hillis-Steele)
    scS[t] = cntS[t]; scS[t + 256] = cntS[t + 256];
    __syncthreads();
    for (int off = 1; off < 512; off <<= 1) {
        int a0 = (t >= off) ? scS[t - off] : 0;
        int a1 = scS[t + 256 - off];
        __syncthreads();
        scS[t] += a0; scS[t + 256] += a1;
        __syncthreads();
    }
    curS[t] = scS[t] - cntS[t];
    curS[t + 256] = scS[t + 256] - cntS[t + 256];
    __syncthreads();
    // pass B: scatter full packed word into LDS by src-bin position
    for (int i = t; i < n; i += 256) {
        unsigned int u = bin[base + i];
        int p = atomicAdd(&curS[(u & 0x3FFFFu) >> BSHIFT], 1);
        if (p < MAXBUCK) payload[p] = u;
    }
    __syncthreads();
    // coalesced in-place write-back (now src-bin sorted)
    for (int i = t; i < n; i += 256) bin[base + i] = payload[i];
    // dinv for this bucket's nodes
    int node0 = b << BSHIFT;
#pragma unroll
    for (int k = 0; k < 2; ++k) {
        int ld = t + k * 256;
        int node = node0 + ld;
        if (node < N_NODES) dinv[node] = rsqrtf((float)cntD[ld] + 1.0f);
    }
}

// h = x @ W  (row-major x: [N, FIN], W: [FIN, FOUT])
template <int FIN, int FOUT>
__global__ void k_xw(const float* __restrict__ x, const float* __restrict__ W,
                     float* __restrict__ h) {
    __shared__ float sW[FIN * FOUT];
    int t = threadIdx.x;
    if (t < FIN * FOUT) sW[t] = W[t];
    __syncthreads();
    int i = blockIdx.x * blockDim.x + t;
    if (i >= N_NODES) return;
    float xi[FIN];
#pragma unroll
    for (int k = 0; k < FIN; ++k) xi[k] = x[i * FIN + k];
#pragma unroll
    for (int j = 0; j < FOUT; ++j) {
        float acc = 0.f;
#pragma unroll
        for (int k = 0; k < FIN; ++k) acc += xi[k] * sW[k * FOUT + j];
        h[i * FOUT + j] = acc;
    }
}

// One block per 512-dst bucket. Edges are src-bin sorted -> h gathers are
// near-sequential (L1/L2-resident window). Accumulate into LDS acc[512][PF]
// via ds_add_f32 (dinv[dst] factored out; applied at write-out).
template <int F, int PF, bool RELU>
__global__ void __launch_bounds__(512)
k_agg_lds(const int* __restrict__ bucketBase, const unsigned int* __restrict__ bin,
          const float* __restrict__ dinv, const float* __restrict__ h,
          const float* __restrict__ bias, float* __restrict__ out) {
    __shared__ float acc[512 * PF];
    __shared__ float dloc[512];
    __shared__ unsigned int sEdge[512];
    __shared__ float sDinv[512];
    int b = blockIdx.x, t = threadIdx.x;
    int base = bucketBase[b];
    int n = bucketBase[b + 1] - base;
    int node0 = b << BSHIFT;
    for (int i = t; i < 512 * PF; i += 512) acc[i] = 0.f;
    if (t < 512) {
        int node = node0 + t;
        dloc[t] = (node < N_NODES) ? dinv[node] : 0.f;
    }
    __syncthreads();
    int g = t >> 4, f = t & 15;   // 32 groups x 16 lanes
    for (int done = 0; done < n; done += 512) {
        int m = min(512, n - done);
        if (t < m) {
            unsigned int u = bin[base + done + t];
            sEdge[t] = u;
            sDinv[t] = dinv[u & 0x3FFFFu];
        }
        __syncthreads();
        if (f < F) {
            for (int k = g; k < m; k += 32) {
                unsigned int u = sEdge[k];
                int src = (int)(u & 0x3FFFFu);
                int ld = (int)(u >> 18);
                float v = h[src * F + f];
                atomicAdd(&acc[ld * PF + f], sDinv[k] * v);
            }
        }
        __syncthreads();
    }
    // epilogue: out = di*acc + di^2*h_self + bias (+relu), coalesced
    int nvalid = min(512, N_NODES - node0);
    int total = nvalid * F;
    for (int i = t; i < total; i += 512) {
        int ld = i / F, ff = i - ld * F;
        float di = dloc[ld];
        float r = di * acc[ld * PF + ff] + di * di * h[(node0 + ld) * F + ff] + bias[ff];
        if (RELU) r = fmaxf(r, 0.f);
        out[node0 * F + i] = r;
    }
}

extern "C" void kernel_launch(void* const* d_in, const int* in_sizes, int n_in,
                              void* d_out, int out_size, void* d_ws, size_t ws_size,
                              hipStream_t stream) {
    const float* x  = (const float*)d_in[0];
    const void*  ei = d_in[1];
    const float* W1 = (const float*)d_in[2];
    const float* b1 = (const float*)d_in[3];
    const float* W2 = (const float*)d_in[4];
    const float* b2 = (const float*)d_in[5];
    const float* W3 = (const float*)d_in[6];
    const float* b3 = (const float*)d_in[7];
    float* out = (float*)d_out;

    char* w = (char*)d_ws;
    int*   bucketCnt    = (int*)(w + 0);        //  2048 B (512 ints, zeroed)
    int*   bucketBase   = (int*)(w + 2048);     //  2048 B
    int*   bucketCursor = (int*)(w + 4096);     //  2048 B
    int*   flag         = (int*)(w + 6144);     //    64 B
    float* dinv         = (float*)(w + 6208);   //  800000 B
    unsigned int* bin   = (unsigned int*)(w + 806208);  // 25600000 B
    float* hbuf         = (float*)(w + 26406208);       // 12800000 B
    float* gbuf         = (float*)(w + 39206208);       //  8800000 B
    // total ~48.0 MB

    // ---- build degree + src-bin-sorted bucketed edges (shared by 3 layers) ----
    k_zero<<<2, 256, 0, stream>>>(bucketCnt, 512);
    k_detect<<<1, 256, 0, stream>>>((const unsigned int*)ei, flag);
    k_hist<<<1024, 256, 0, stream>>>(ei, flag, bucketCnt);
    k_scan_buckets<<<1, 256, 0, stream>>>(bucketCnt, bucketBase, bucketCursor);
    k_binscatter<<<NCHUNK, 256, 0, stream>>>(ei, flag, bucketCursor, bin);
    k_bucketsort<<<NBUCK, 256, 0, stream>>>(bucketBase, bin, dinv);

    // ---- layer 1: relu(gcn(x, W1, b1)) ----
    k_xw<11, 11><<<782, 256, 0, stream>>>(x, W1, hbuf);
    k_agg_lds<11, 12, true><<<NBUCK, 512, 0, stream>>>(bucketBase, bin, dinv, hbuf, b1, gbuf);
    // ---- layer 2: relu(gcn(g, W2, b2)) ----
    k_xw<11, 11><<<782, 256, 0, stream>>>(gbuf, W2, hbuf);
    k_agg_lds<11, 12, true><<<NBUCK, 512, 0, stream>>>(bucketBase, bin, dinv, hbuf, b2, gbuf);
    // ---- layer 3: gcn(g, W3, b3) ----
    k_xw<11, 16><<<782, 256, 0, stream>>>(gbuf, W3, hbuf);
    k_agg_lds<16, 17, false><<<NBUCK, 512, 0, stream>>>(bucketBase, bin, dinv, hbuf, b3, out);
}

// Round 4
// 1645.819 us; speedup vs baseline: 1.1454x; 1.1454x over previous
//
#include <hip/hip_runtime.h>

#define N_NODES 200000
#define N_EDGES 6400000

constexpr int BSHIFT = 9;                      // 512 nodes per bucket
constexpr int NBUCK  = (N_NODES + 511) / 512;  // 391
constexpr int CHUNK  = 16384;
constexpr int NCHUNK = (N_EDGES + CHUNK - 1) / CHUNK;  // 391
constexpr int MAXBUCK = 18432;                 // lambda=16384, +16 sigma
constexpr int NSEG   = 4;                      // src-range segments per bucket

// ---- edge index load helper: handles int32 or int64 storage ----
__device__ __forceinline__ int ld_edge(const void* ei, int is64, int idx) {
    return is64 ? (int)((const long long*)ei)[idx] : ((const int*)ei)[idx];
}

__device__ __forceinline__ void lds_fadd(float* p, float v) {
    __hip_atomic_fetch_add(p, v, __ATOMIC_RELAXED, __HIP_MEMORY_SCOPE_WORKGROUP);
}

__global__ void k_zero(int* __restrict__ p, int n) {
    int i = blockIdx.x * blockDim.x + threadIdx.x;
    if (i < n) p[i] = 0;
}

// int64 little-endian values < 2^31  =>  every odd u32 slot is 0
__global__ void k_detect(const unsigned int* __restrict__ ei, int* __restrict__ flag) {
    __shared__ int nz;
    if (threadIdx.x == 0) nz = 0;
    __syncthreads();
    if (ei[2 * threadIdx.x + 1] != 0u) atomicOr(&nz, 1);
    __syncthreads();
    if (threadIdx.x == 0) *flag = nz ? 0 : 1;
}

// bucket histogram: LDS-accumulated, one global atomic per bucket per block
__global__ void k_hist(const void* __restrict__ ei, const int* __restrict__ flag,
                       int* __restrict__ bucketCnt) {
    __shared__ int h[NBUCK];
    for (int i = threadIdx.x; i < NBUCK; i += 256) h[i] = 0;
    __syncthreads();
    const int is64 = *flag;
    int stride = gridDim.x * blockDim.x;
    for (int e = blockIdx.x * 256 + threadIdx.x; e < N_EDGES; e += stride) {
        int d = ld_edge(ei, is64, N_EDGES + e);
        atomicAdd(&h[d >> BSHIFT], 1);
    }
    __syncthreads();
    for (int i = threadIdx.x; i < NBUCK; i += 256)
        if (h[i]) atomicAdd(&bucketCnt[i], h[i]);
}

// single-block scan of 391 bucket counts -> exclusive bases + cursors
__global__ void k_scan_buckets(const int* __restrict__ bucketCnt,
                               int* __restrict__ bucketBase,
                               int* __restrict__ bucketCursor) {
    __shared__ int sc[512];
    int t = threadIdx.x;
    sc[t]       = (t < NBUCK)       ? bucketCnt[t]       : 0;
    sc[t + 256] = (t + 256 < NBUCK) ? bucketCnt[t + 256] : 0;
    __syncthreads();
    for (int off = 1; off < 512; off <<= 1) {
        int a0 = (t >= off) ? sc[t - off] : 0;
        int a1 = sc[t + 256 - off];
        __syncthreads();
        sc[t] += a0; sc[t + 256] += a1;
        __syncthreads();
    }
    for (int i = t; i < NBUCK; i += 256) {
        int excl = sc[i] - bucketCnt[i];
        bucketBase[i] = excl;
        bucketCursor[i] = excl;
    }
    if (t == 0) bucketBase[NBUCK] = N_EDGES;
}

// level-1: bin a 16K-edge chunk by bucket in LDS, write contiguous runs
__global__ void __launch_bounds__(256)
k_binscatter(const void* __restrict__ ei, const int* __restrict__ flag,
             int* __restrict__ bucketCursor, unsigned int* __restrict__ bin) {
    __shared__ int hist[NBUCK];
    __shared__ int pref[NBUCK + 1];
    __shared__ int cur[NBUCK];
    __shared__ int gb[NBUCK];
    __shared__ int sc[512];
    __shared__ unsigned int stage[CHUNK];
    const int is64 = *flag;
    int b = blockIdx.x, t = threadIdx.x;
    int e0 = b * CHUNK;
    int n = min(CHUNK, N_EDGES - e0);
    for (int i = t; i < NBUCK; i += 256) hist[i] = 0;
    __syncthreads();
    // pass A: per-chunk bucket histogram
    for (int i = t; i < n; i += 256) {
        int d = ld_edge(ei, is64, N_EDGES + e0 + i);
        atomicAdd(&hist[d >> BSHIFT], 1);
    }
    __syncthreads();
    // scan histogram (512-slot Hillis-Steele)
    sc[t]       = (t < NBUCK)       ? hist[t]       : 0;
    sc[t + 256] = (t + 256 < NBUCK) ? hist[t + 256] : 0;
    __syncthreads();
    for (int off = 1; off < 512; off <<= 1) {
        int a0 = (t >= off) ? sc[t - off] : 0;
        int a1 = sc[t + 256 - off];
        __syncthreads();
        sc[t] += a0; sc[t + 256] += a1;
        __syncthreads();
    }
    for (int i = t; i < NBUCK; i += 256) {
        int excl = sc[i] - hist[i];
        pref[i] = excl;
        cur[i] = excl;
    }
    if (t == 0) pref[NBUCK] = n;
    __syncthreads();
    // pass B: scatter packed (local_d<<18 | src) into LDS stage, bucket-grouped
    for (int i = t; i < n; i += 256) {
        int s = ld_edge(ei, is64, e0 + i);
        int d = ld_edge(ei, is64, N_EDGES + e0 + i);
        int bk = d >> BSHIFT;
        int p = atomicAdd(&cur[bk], 1);
        stage[p] = ((unsigned int)(d & 511) << 18) | (unsigned int)s;
    }
    __syncthreads();
    // reserve global ranges, one atomic per non-empty bucket
    for (int i = t; i < NBUCK; i += 256) {
        int c = hist[i];
        gb[i] = c ? atomicAdd(&bucketCursor[i], c) : 0;
    }
    __syncthreads();
    // write out contiguous runs (binary-search bucket per slot)
    for (int p = t; p < n; p += 256) {
        int lo = 0, hi = NBUCK;
        while (hi - lo > 1) {
            int mid = (lo + hi) >> 1;
            if (pref[mid] <= p) lo = mid; else hi = mid;
        }
        bin[gb[lo] + (p - pref[lo])] = stage[p];
    }
}

// level-2: one block per bucket. Re-sort the bucket's edges by SRC-BIN
// (src>>9), record NSEG src-range segment offsets, produce dinv from degrees.
__global__ void __launch_bounds__(256)
k_bucketsort(const int* __restrict__ bucketBase, unsigned int* __restrict__ bin,
             float* __restrict__ dinv, int* __restrict__ segOff) {
    __shared__ int cntS[512];
    __shared__ int scS[512];
    __shared__ int curS[512];
    __shared__ int cntD[512];
    __shared__ unsigned int payload[MAXBUCK];
    int b = blockIdx.x, t = threadIdx.x;
    int base = bucketBase[b], end = bucketBase[b + 1];
    int n = end - base;
    cntS[t] = 0; cntS[t + 256] = 0;
    cntD[t] = 0; cntD[t + 256] = 0;
    __syncthreads();
    // pass A: src-bin histogram + per-node (dst) degree
    for (int i = t; i < n; i += 256) {
        unsigned int u = bin[base + i];
        atomicAdd(&cntS[(u & 0x3FFFFu) >> BSHIFT], 1);
        atomicAdd(&cntD[u >> 18], 1);
    }
    __syncthreads();
    // scan cntS (512-slot Hillis-Steele)
    scS[t] = cntS[t]; scS[t + 256] = cntS[t + 256];
    __syncthreads();
    for (int off = 1; off < 512; off <<= 1) {
        int a0 = (t >= off) ? scS[t - off] : 0;
        int a1 = scS[t + 256 - off];
        __syncthreads();
        scS[t] += a0; scS[t + 256] += a1;
        __syncthreads();
    }
    curS[t] = scS[t] - cntS[t];
    curS[t + 256] = scS[t + 256] - cntS[t + 256];
    __syncthreads();
    // segment offsets at src-bin boundaries q*NBUCK/NSEG
    if (t < NSEG) {
        int Bq = (NBUCK * t) / NSEG;            // 0, 97, 195, 293
        segOff[b * NSEG + t] = base + (scS[Bq] - cntS[Bq]);
    }
    // pass B: scatter full packed word into LDS by src-bin position
    for (int i = t; i < n; i += 256) {
        unsigned int u = bin[base + i];
        int p = atomicAdd(&curS[(u & 0x3FFFFu) >> BSHIFT], 1);
        if (p < MAXBUCK) payload[p] = u;
    }
    __syncthreads();
    // coalesced in-place write-back (now src-bin sorted)
    for (int i = t; i < n; i += 256) bin[base + i] = payload[i];
    // dinv for this bucket's nodes
    int node0 = b << BSHIFT;
#pragma unroll
    for (int k = 0; k < 2; ++k) {
        int ld = t + k * 256;
        int node = node0 + ld;
        if (node < N_NODES) dinv[node] = rsqrtf((float)cntD[ld] + 1.0f);
    }
}

// hs = dinv[i] * (x @ W), padded to stride 16 (one 64B line per row).
// Safe in-place (xin may alias hs): row is loaded to regs before stores.
template <int FIN, int FOUT, int SIN>
__global__ void k_xw(const float* xin, const float* __restrict__ W,
                     const float* __restrict__ dinv, float* hs) {
    __shared__ float sW[FIN * FOUT];
    int t = threadIdx.x;
    if (t < FIN * FOUT) sW[t] = W[t];
    __syncthreads();
    int i = blockIdx.x * 256 + t;
    if (i >= N_NODES) return;
    float xi[FIN];
#pragma unroll
    for (int k = 0; k < FIN; ++k) xi[k] = xin[i * SIN + k];
    float di = dinv[i];
    float o[FOUT];
#pragma unroll
    for (int j = 0; j < FOUT; ++j) {
        float acc = 0.f;
#pragma unroll
        for (int k = 0; k < FIN; ++k) acc += xi[k] * sW[k * FOUT + j];
        o[j] = di * acc;
    }
#pragma unroll
    for (int j = 0; j < FOUT; ++j) hs[i * 16 + j] = o[j];
}

// One block per (bucket, src-segment). Barrier-free unrolled edge loop,
// LDS ds_add_f32 accumulate, coalesced global-atomic flush into accG.
template <int F>
__global__ void __launch_bounds__(512)
k_agg(const int* __restrict__ bucketBase, const int* __restrict__ segOff,
      const unsigned int* __restrict__ bin, const float* __restrict__ hs,
      float* __restrict__ accG) {
    __shared__ float acc[512 * 17];
    int blk = blockIdx.x;
    int b = blk >> 2, q = blk & 3;
    int t = threadIdx.x;
    for (int i = t; i < 512 * 17; i += 512) acc[i] = 0.f;
    __syncthreads();
    int start = segOff[b * NSEG + q];
    int end = (q == NSEG - 1) ? bucketBase[b + 1] : segOff[b * NSEG + q + 1];
    int g = t >> 4, f = t & 15;   // 32 groups x 16 lanes
    if (f < F) {
        int k = start + g;
        for (; k + 96 < end; k += 128) {
            unsigned int u0 = bin[k];
            unsigned int u1 = bin[k + 32];
            unsigned int u2 = bin[k + 64];
            unsigned int u3 = bin[k + 96];
            float v0 = hs[((u0 & 0x3FFFFu) << 4) + f];
            float v1 = hs[((u1 & 0x3FFFFu) << 4) + f];
            float v2 = hs[((u2 & 0x3FFFFu) << 4) + f];
            float v3 = hs[((u3 & 0x3FFFFu) << 4) + f];
            lds_fadd(&acc[(u0 >> 18) * 17 + f], v0);
            lds_fadd(&acc[(u1 >> 18) * 17 + f], v1);
            lds_fadd(&acc[(u2 >> 18) * 17 + f], v2);
            lds_fadd(&acc[(u3 >> 18) * 17 + f], v3);
        }
        for (; k < end; k += 32) {
            unsigned int u = bin[k];
            float v = hs[((u & 0x3FFFFu) << 4) + f];
            lds_fadd(&acc[(u >> 18) * 17 + f], v);
        }
    }
    __syncthreads();
    int node0 = b << BSHIFT;
    int nvalid = min(512, N_NODES - node0);
    for (int i = t; i < nvalid * 16; i += 512) {
        int ld = i >> 4, ff = i & 15;
        if (ff < F)
            unsafeAtomicAdd(&accG[((node0 + ld) << 4) + ff], acc[ld * 17 + ff]);
    }
}

// out = relu?(dinv*(accG + hs_self) + bias); re-zeros accG for next layer.
template <int F, bool RELU, bool TOOUT>
__global__ void k_finish(float* __restrict__ B, float* __restrict__ accG,
                         const float* __restrict__ dinv,
                         const float* __restrict__ bias, float* __restrict__ out) {
    int i = blockIdx.x * blockDim.x + threadIdx.x;
    if (i >= N_NODES * 16) return;
    int node = i >> 4, ff = i & 15;
    if (ff < F) {
        float di = dinv[node];
        float r = di * (accG[i] + B[i]) + bias[ff];
        if (RELU) r = fmaxf(r, 0.f);
        if (TOOUT) out[node * F + ff] = r;
        else       B[i] = r;
        accG[i] = 0.f;
    }
}

extern "C" void kernel_launch(void* const* d_in, const int* in_sizes, int n_in,
                              void* d_out, int out_size, void* d_ws, size_t ws_size,
                              hipStream_t stream) {
    const float* x  = (const float*)d_in[0];
    const void*  ei = d_in[1];
    const float* W1 = (const float*)d_in[2];
    const float* b1 = (const float*)d_in[3];
    const float* W2 = (const float*)d_in[4];
    const float* b2 = (const float*)d_in[5];
    const float* W3 = (const float*)d_in[6];
    const float* b3 = (const float*)d_in[7];
    float* out = (float*)d_out;

    char* w = (char*)d_ws;
    int*   bucketCnt    = (int*)(w + 0);        //   2048 B (512 ints, zeroed)
    int*   bucketBase   = (int*)(w + 2048);     //   2048 B
    int*   bucketCursor = (int*)(w + 4096);     //   2048 B
    int*   flag         = (int*)(w + 6144);     //     64 B
    int*   segOff       = (int*)(w + 6208);     //   6400 B (391*4 ints)
    float* dinv         = (float*)(w + 12608);  // 800000 B
    unsigned int* bin   = (unsigned int*)(w + 812608);  // 25600000 B
    float* B            = (float*)(w + 26412608);       // 12800000 B (N*16)
    float* accG         = (float*)(w + 39212608);       // 12800000 B (N*16)
    // total ~52.0 MB

    // ---- zero accumulator + build src-bin-sorted bucketed edges ----
    k_zero<<<12500, 256, 0, stream>>>((int*)accG, N_NODES * 16);
    k_zero<<<2, 256, 0, stream>>>(bucketCnt, 512);
    k_detect<<<1, 256, 0, stream>>>((const unsigned int*)ei, flag);
    k_hist<<<1024, 256, 0, stream>>>(ei, flag, bucketCnt);
    k_scan_buckets<<<1, 256, 0, stream>>>(bucketCnt, bucketBase, bucketCursor);
    k_binscatter<<<NCHUNK, 256, 0, stream>>>(ei, flag, bucketCursor, bin);
    k_bucketsort<<<NBUCK, 256, 0, stream>>>(bucketBase, bin, dinv, segOff);

    // ---- layer 1 ----
    k_xw<11, 11, 11><<<782, 256, 0, stream>>>(x, W1, dinv, B);
    k_agg<11><<<NBUCK * NSEG, 512, 0, stream>>>(bucketBase, segOff, bin, B, accG);
    k_finish<11, true, false><<<12500, 256, 0, stream>>>(B, accG, dinv, b1, out);
    // ---- layer 2 ----
    k_xw<11, 11, 16><<<782, 256, 0, stream>>>(B, W2, dinv, B);
    k_agg<11><<<NBUCK * NSEG, 512, 0, stream>>>(bucketBase, segOff, bin, B, accG);
    k_finish<11, true, false><<<12500, 256, 0, stream>>>(B, accG, dinv, b2, out);
    // ---- layer 3 ----
    k_xw<11, 16, 16><<<782, 256, 0, stream>>>(B, W3, dinv, B);
    k_agg<16><<<NBUCK * NSEG, 512, 0, stream>>>(bucketBase, segOff, bin, B, accG);
    k_finish<16, false, true><<<12500, 256, 0, stream>>>(B, accG, dinv, b3, out);
}

// Round 5
// 677.363 us; speedup vs baseline: 2.7832x; 2.4297x over previous
//
#include <hip/hip_runtime.h>

#define N_NODES 200000
#define N_EDGES 6400000

constexpr int BSHIFT = 9;                      // 512 nodes per bucket
constexpr int NBUCK  = (N_NODES + 511) / 512;  // 391
constexpr int CHUNK  = 16384;
constexpr int NCHUNK = (N_EDGES + CHUNK - 1) / CHUNK;  // 391
constexpr int MAXBUCK = 18432;                 // lambda=16384, +16 sigma
constexpr int NSEG   = 4;                      // src-range segments (q = src/50000)
constexpr int SEGSTRIDE = 2052;                // 2048 bins + end sentinel + pad

// ---- edge index load helper: handles int32 or int64 storage ----
__device__ __forceinline__ int ld_edge(const void* ei, int is64, int idx) {
    return is64 ? (int)((const long long*)ei)[idx] : ((const int*)ei)[idx];
}

__global__ void k_zero(int* __restrict__ p, int n) {
    int i = blockIdx.x * blockDim.x + threadIdx.x;
    if (i < n) p[i] = 0;
}

// int64 little-endian values < 2^31  =>  every odd u32 slot is 0
__global__ void k_detect(const unsigned int* __restrict__ ei, int* __restrict__ flag) {
    __shared__ int nz;
    if (threadIdx.x == 0) nz = 0;
    __syncthreads();
    if (ei[2 * threadIdx.x + 1] != 0u) atomicOr(&nz, 1);
    __syncthreads();
    if (threadIdx.x == 0) *flag = nz ? 0 : 1;
}

// bucket histogram: LDS-accumulated, one global atomic per bucket per block
__global__ void k_hist(const void* __restrict__ ei, const int* __restrict__ flag,
                       int* __restrict__ bucketCnt) {
    __shared__ int h[NBUCK];
    for (int i = threadIdx.x; i < NBUCK; i += 256) h[i] = 0;
    __syncthreads();
    const int is64 = *flag;
    int stride = gridDim.x * blockDim.x;
    for (int e = blockIdx.x * 256 + threadIdx.x; e < N_EDGES; e += stride) {
        int d = ld_edge(ei, is64, N_EDGES + e);
        atomicAdd(&h[d >> BSHIFT], 1);
    }
    __syncthreads();
    for (int i = threadIdx.x; i < NBUCK; i += 256)
        if (h[i]) atomicAdd(&bucketCnt[i], h[i]);
}

// single-block scan of 391 bucket counts -> exclusive bases + cursors
__global__ void k_scan_buckets(const int* __restrict__ bucketCnt,
                               int* __restrict__ bucketBase,
                               int* __restrict__ bucketCursor) {
    __shared__ int sc[512];
    int t = threadIdx.x;
    sc[t]       = (t < NBUCK)       ? bucketCnt[t]       : 0;
    sc[t + 256] = (t + 256 < NBUCK) ? bucketCnt[t + 256] : 0;
    __syncthreads();
    for (int off = 1; off < 512; off <<= 1) {
        int a0 = (t >= off) ? sc[t - off] : 0;
        int a1 = sc[t + 256 - off];
        __syncthreads();
        sc[t] += a0; sc[t + 256] += a1;
        __syncthreads();
    }
    for (int i = t; i < NBUCK; i += 256) {
        int excl = sc[i] - bucketCnt[i];
        bucketBase[i] = excl;
        bucketCursor[i] = excl;
    }
    if (t == 0) bucketBase[NBUCK] = N_EDGES;
}

// level-1: bin a 16K-edge chunk by bucket in LDS, write contiguous runs
__global__ void __launch_bounds__(256)
k_binscatter(const void* __restrict__ ei, const int* __restrict__ flag,
             int* __restrict__ bucketCursor, unsigned int* __restrict__ bin) {
    __shared__ int hist[NBUCK];
    __shared__ int pref[NBUCK + 1];
    __shared__ int cur[NBUCK];
    __shared__ int gb[NBUCK];
    __shared__ int sc[512];
    __shared__ unsigned int stage[CHUNK];
    const int is64 = *flag;
    int b = blockIdx.x, t = threadIdx.x;
    int e0 = b * CHUNK;
    int n = min(CHUNK, N_EDGES - e0);
    for (int i = t; i < NBUCK; i += 256) hist[i] = 0;
    __syncthreads();
    for (int i = t; i < n; i += 256) {
        int d = ld_edge(ei, is64, N_EDGES + e0 + i);
        atomicAdd(&hist[d >> BSHIFT], 1);
    }
    __syncthreads();
    sc[t]       = (t < NBUCK)       ? hist[t]       : 0;
    sc[t + 256] = (t + 256 < NBUCK) ? hist[t + 256] : 0;
    __syncthreads();
    for (int off = 1; off < 512; off <<= 1) {
        int a0 = (t >= off) ? sc[t - off] : 0;
        int a1 = sc[t + 256 - off];
        __syncthreads();
        sc[t] += a0; sc[t + 256] += a1;
        __syncthreads();
    }
    for (int i = t; i < NBUCK; i += 256) {
        int excl = sc[i] - hist[i];
        pref[i] = excl;
        cur[i] = excl;
    }
    if (t == 0) pref[NBUCK] = n;
    __syncthreads();
    for (int i = t; i < n; i += 256) {
        int s = ld_edge(ei, is64, e0 + i);
        int d = ld_edge(ei, is64, N_EDGES + e0 + i);
        int bk = d >> BSHIFT;
        int p = atomicAdd(&cur[bk], 1);
        stage[p] = ((unsigned int)(d & 511) << 18) | (unsigned int)s;
    }
    __syncthreads();
    for (int i = t; i < NBUCK; i += 256) {
        int c = hist[i];
        gb[i] = c ? atomicAdd(&bucketCursor[i], c) : 0;
    }
    __syncthreads();
    for (int p = t; p < n; p += 256) {
        int lo = 0, hi = NBUCK;
        while (hi - lo > 1) {
            int mid = (lo + hi) >> 1;
            if (pref[mid] <= p) lo = mid; else hi = mid;
        }
        bin[gb[lo] + (p - pref[lo])] = stage[p];
    }
}

// level-2: one block per bucket. Counting-sort the bucket's edges by key
// (q<<9)|local_dst (q = src/50000), emit per-(q,dst) u16 rowptr + dinv.
__global__ void __launch_bounds__(256)
k_bucketsort(const int* __restrict__ bucketBase, unsigned int* __restrict__ bin,
             float* __restrict__ dinv, unsigned short* __restrict__ seg16) {
    __shared__ int cnt[2048];
    __shared__ int cur[2048];
    __shared__ int tsum[256];
    __shared__ unsigned int payload[MAXBUCK];
    int b = blockIdx.x, t = threadIdx.x;
    int base = bucketBase[b], end = bucketBase[b + 1];
    int n = end - base;
    for (int i = t; i < 2048; i += 256) cnt[i] = 0;
    __syncthreads();
    // pass A: histogram over 2048 (q, local_dst) bins
    for (int i = t; i < n; i += 256) {
        unsigned int u = bin[base + i];
        int src = (int)(u & 0x3FFFFu);
        int key = ((src / 50000) << 9) | (int)(u >> 18);
        atomicAdd(&cnt[key], 1);
    }
    __syncthreads();
    // scan 2048: serial-8 per thread + Hillis-Steele over 256 thread sums
    int b0 = t * 8;
    int s = 0;
#pragma unroll
    for (int j = 0; j < 8; ++j) s += cnt[b0 + j];
    tsum[t] = s;
    __syncthreads();
    int v = s;
    for (int off = 1; off < 256; off <<= 1) {
        int add = (t >= off) ? tsum[t - off] : 0;
        __syncthreads();
        tsum[t] += add;
        __syncthreads();
    }
    int run = tsum[t] - v;  // exclusive prefix of this thread's chunk
#pragma unroll
    for (int j = 0; j < 8; ++j) { cur[b0 + j] = run; run += cnt[b0 + j]; }
    __syncthreads();
    // write u16 relative rowptr (before scatter mutates cur) + sentinel + dinv
    for (int i = t; i < 2048; i += 256)
        seg16[b * SEGSTRIDE + i] = (unsigned short)cur[i];
    if (t == 0) seg16[b * SEGSTRIDE + 2048] = (unsigned short)n;
    int node0 = b << BSHIFT;
    for (int d = t; d < 512; d += 256) {
        int node = node0 + d;
        if (node < N_NODES) {
            int deg = cnt[d] + cnt[512 + d] + cnt[1024 + d] + cnt[1536 + d];
            dinv[node] = rsqrtf((float)deg + 1.0f);
        }
    }
    __syncthreads();
    // pass B: scatter into payload by final position
    for (int i = t; i < n; i += 256) {
        unsigned int u = bin[base + i];
        int src = (int)(u & 0x3FFFFu);
        int key = ((src / 50000) << 9) | (int)(u >> 18);
        int p = atomicAdd(&cur[key], 1);
        if (p < MAXBUCK) payload[p] = u;
    }
    __syncthreads();
    // coalesced in-place write-back (sorted by (q, local_dst))
    for (int i = t; i < n; i += 256) bin[base + i] = payload[i];
}

// hs = dinv[i] * (x @ W), padded to stride 16 (one 64B line per row).
// Safe in-place (xin may alias hs): row is loaded to regs before stores.
template <int FIN, int FOUT, int SIN>
__global__ void k_xw(const float* xin, const float* __restrict__ W,
                     const float* __restrict__ dinv, float* hs) {
    __shared__ float sW[FIN * FOUT];
    int t = threadIdx.x;
    if (t < FIN * FOUT) sW[t] = W[t];
    __syncthreads();
    int i = blockIdx.x * 256 + t;
    if (i >= N_NODES) return;
    float xi[FIN];
#pragma unroll
    for (int k = 0; k < FIN; ++k) xi[k] = xin[i * SIN + k];
    float di = dinv[i];
    float o[FOUT];
#pragma unroll
    for (int j = 0; j < FOUT; ++j) {
        float acc = 0.f;
#pragma unroll
        for (int k = 0; k < FIN; ++k) acc += xi[k] * sW[k * FOUT + j];
        o[j] = di * acc;
    }
#pragma unroll
    for (int j = 0; j < FOUT; ++j) hs[i * 16 + j] = o[j];
}

// One block per (bucket, q-segment); 32 groups x 16 lanes. Group g owns
// dsts [g*16, g*16+16): walks each (q,dst)'s contiguous edge run with a
// REGISTER accumulator (no LDS, no per-edge atomics), then one coalesced
// global_atomic_add_f32 per (dst, f). blk = b*4+q keeps q == XCD%4 so each
// XCD's gathers stay in a 3.2 MB hs window (L2-resident).
__global__ void __launch_bounds__(512)
k_agg(const int* __restrict__ bucketBase, const unsigned short* __restrict__ seg16,
      const unsigned int* __restrict__ bin, const float* __restrict__ hs,
      float* __restrict__ accG) {
    int blk = blockIdx.x;
    int b = blk >> 2, q = blk & 3;
    int t = threadIdx.x;
    int g = t >> 4, f = t & 15;
    int node0 = b << BSHIFT;
    int base = bucketBase[b];
    const unsigned short* sr = seg16 + b * SEGSTRIDE + (q << 9);
    int d0 = g << 4;
    int bLo = (int)sr[d0 + f];     // lane f holds relative start of dst d0+f
    int bHi = (int)sr[d0 + 16];    // start of next group's range (or q/bucket end)
    int wbase = t & 48;            // group base lane within wave
#pragma unroll 1
    for (int j = 0; j < 16; ++j) {
        int e0 = base + __shfl(bLo, wbase + j);
        int e1 = base + ((j < 15) ? __shfl(bLo, wbase + j + 1) : bHi);
        float acc0 = 0.f, acc1 = 0.f;
        int e = e0;
        for (; e + 1 < e1; e += 2) {
            unsigned int ua = bin[e];
            unsigned int ub = bin[e + 1];
            acc0 += hs[((ua & 0x3FFFFu) << 4) + f];
            acc1 += hs[((ub & 0x3FFFFu) << 4) + f];
        }
        if (e < e1) {
            unsigned int ua = bin[e];
            acc0 += hs[((ua & 0x3FFFFu) << 4) + f];
        }
        int node = node0 + d0 + j;
        if (node < N_NODES)
            unsafeAtomicAdd(&accG[(node << 4) + f], acc0 + acc1);
    }
}

// out = relu?(dinv*(accG + hs_self) + bias); re-zeros accG (aliases d_out).
template <int F, bool RELU, bool TOOUT>
__global__ void k_finish(float* __restrict__ B, float* __restrict__ accG,
                         const float* __restrict__ dinv,
                         const float* __restrict__ bias, float* __restrict__ out) {
    int i = blockIdx.x * blockDim.x + threadIdx.x;
    if (i >= N_NODES * 16) return;
    int node = i >> 4, ff = i & 15;
    float di = dinv[node];
    if (ff < F) {
        float r = di * (accG[i] + B[i]) + bias[ff];
        if (RELU) r = fmaxf(r, 0.f);
        if (TOOUT) out[node * 16 + ff] = r;   // layer 3: F==16, in-place (accG==out)
        else       B[i] = r;
    }
    if (!TOOUT) accG[i] = 0.f;
}

extern "C" void kernel_launch(void* const* d_in, const int* in_sizes, int n_in,
                              void* d_out, int out_size, void* d_ws, size_t ws_size,
                              hipStream_t stream) {
    const float* x  = (const float*)d_in[0];
    const void*  ei = d_in[1];
    const float* W1 = (const float*)d_in[2];
    const float* b1 = (const float*)d_in[3];
    const float* W2 = (const float*)d_in[4];
    const float* b2 = (const float*)d_in[5];
    const float* W3 = (const float*)d_in[6];
    const float* b3 = (const float*)d_in[7];
    float* out = (float*)d_out;

    char* w = (char*)d_ws;
    int*   bucketCnt    = (int*)(w + 0);        //    2048 B (512 ints, zeroed)
    int*   bucketBase   = (int*)(w + 2048);     //    2048 B
    int*   bucketCursor = (int*)(w + 4096);     //    2048 B
    int*   flag         = (int*)(w + 6144);     //      64 B
    float* dinv         = (float*)(w + 6208);   //  800000 B
    unsigned short* seg16 = (unsigned short*)(w + 806208); // 391*2052*2 = 1604664 B
    unsigned int* bin   = (unsigned int*)(w + 2410880);    // 25600000 B
    float* B            = (float*)(w + 28010880);          // 12800000 B (N*16)
    float* accG         = out;                  // d_out doubles as accumulator
    // total ws use ~40.8 MB

    // ---- zero accumulator (d_out) + build (q,dst)-sorted bucketed edges ----
    k_zero<<<12500, 256, 0, stream>>>((int*)accG, N_NODES * 16);
    k_zero<<<2, 256, 0, stream>>>(bucketCnt, 512);
    k_detect<<<1, 256, 0, stream>>>((const unsigned int*)ei, flag);
    k_hist<<<1024, 256, 0, stream>>>(ei, flag, bucketCnt);
    k_scan_buckets<<<1, 256, 0, stream>>>(bucketCnt, bucketBase, bucketCursor);
    k_binscatter<<<NCHUNK, 256, 0, stream>>>(ei, flag, bucketCursor, bin);
    k_bucketsort<<<NBUCK, 256, 0, stream>>>(bucketBase, bin, dinv, seg16);

    // ---- layer 1 ----
    k_xw<11, 11, 11><<<782, 256, 0, stream>>>(x, W1, dinv, B);
    k_agg<<<NBUCK * NSEG, 512, 0, stream>>>(bucketBase, seg16, bin, B, accG);
    k_finish<11, true, false><<<12500, 256, 0, stream>>>(B, accG, dinv, b1, out);
    // ---- layer 2 ----
    k_xw<11, 11, 16><<<782, 256, 0, stream>>>(B, W2, dinv, B);
    k_agg<<<NBUCK * NSEG, 512, 0, stream>>>(bucketBase, seg16, bin, B, accG);
    k_finish<11, true, false><<<12500, 256, 0, stream>>>(B, accG, dinv, b2, out);
    // ---- layer 3 ----
    k_xw<11, 16, 16><<<782, 256, 0, stream>>>(B, W3, dinv, B);
    k_agg<<<NBUCK * NSEG, 512, 0, stream>>>(bucketBase, seg16, bin, B, accG);
    k_finish<16, false, true><<<12500, 256, 0, stream>>>(B, accG, dinv, b3, out);
}